// Round 4
// baseline (202.787 us; speedup 1.0000x reference)
//
#include <hip/hip_runtime.h>
#include <math.h>

#define D      256
#define NSEC   10
#define EPS    1e-6f
#define SLICE  0.1f

// ws float layout
#define WS_SUMS 0                      // [0,2560) per-sector sums
#define WS_CNT  (NSEC * D)             // [2560,2570) per-sector counts
#define WS_DIST (NSEC * D + NSEC)      // [2570] distance accumulator
#define WS_DONE (NSEC * D + NSEC + 1)  // [2571] done-block counter (uint bits)
#define WS_ZERO_FLOATS (NSEC * D + NSEC + 2)

__global__ void k_zero(float* __restrict__ ws) {
    int i = blockIdx.x * blockDim.x + threadIdx.x;
    if (i < WS_ZERO_FLOATS) ws[i] = 0.f;
}

__global__ __launch_bounds__(256) void k_sums(const float* __restrict__ emb,
                                              const int* __restrict__ sec,
                                              float* __restrict__ ws, int nrows) {
    const int lane = threadIdx.x & 63;
    const int wid  = threadIdx.x >> 6;          // 0..3
    const int gw   = blockIdx.x * 4 + wid;      // global wave id
    const int nw   = gridDim.x * 4;

    float4 acc[NSEC];
    float  cnt[NSEC];
#pragma unroll
    for (int s = 0; s < NSEC; ++s) { acc[s] = make_float4(0.f, 0.f, 0.f, 0.f); cnt[s] = 0.f; }

    const float* ep = emb + (size_t)lane * 4;

    auto accum = [&](int sv, float4 v) {
        const int s = __builtin_amdgcn_readfirstlane(sv);  // wave-uniform -> SGPR branch
#pragma unroll
        for (int ss = 0; ss < NSEC; ++ss) {
            if (s == ss) {   // scalar branch; acc index compile-time constant (no scratch)
                acc[ss].x += v.x; acc[ss].y += v.y; acc[ss].z += v.z; acc[ss].w += v.w;
                cnt[ss] += 1.f;
            }
        }
    };

    int r = gw;
    // unroll-4: 4 KB in flight per wave; 16 waves/CU (grid 1024) hides latency
    for (; r + 3 * nw < nrows; r += 4 * nw) {
        const int s0 = sec[r];
        const int s1 = sec[r + nw];
        const int s2 = sec[r + 2 * nw];
        const int s3 = sec[r + 3 * nw];
        const float4 v0 = *reinterpret_cast<const float4*>(ep + (size_t)r * D);
        const float4 v1 = *reinterpret_cast<const float4*>(ep + (size_t)(r + nw) * D);
        const float4 v2 = *reinterpret_cast<const float4*>(ep + (size_t)(r + 2 * nw) * D);
        const float4 v3 = *reinterpret_cast<const float4*>(ep + (size_t)(r + 3 * nw) * D);
        accum(s0, v0); accum(s1, v1); accum(s2, v2); accum(s3, v3);
    }
    for (; r < nrows; r += nw)
        accum(sec[r], *reinterpret_cast<const float4*>(ep + (size_t)r * D));

    __shared__ float lsum[NSEC * D];   // 10 KB -> LDS never caps occupancy
    __shared__ float lcnt[NSEC];
    for (int i = threadIdx.x; i < NSEC * D; i += 256) lsum[i] = 0.f;
    if (threadIdx.x < NSEC) lcnt[threadIdx.x] = 0.f;
    __syncthreads();

    // 4 serialized wave phases: no LDS atomics, no intra-wave address overlap
    for (int w = 0; w < 4; ++w) {
        if (wid == w) {
#pragma unroll
            for (int ss = 0; ss < NSEC; ++ss) {
                float* p = &lsum[ss * D + lane * 4];
                p[0] += acc[ss].x; p[1] += acc[ss].y; p[2] += acc[ss].z; p[3] += acc[ss].w;
                if (lane == 0) lcnt[ss] += cnt[ss];
            }
        }
        __syncthreads();
    }

#pragma unroll
    for (int ss = 0; ss < NSEC; ++ss)
        atomicAdd(&ws[WS_SUMS + ss * D + threadIdx.x], lsum[ss * D + threadIdx.x]);
    if (threadIdx.x < NSEC)
        atomicAdd(&ws[WS_CNT + threadIdx.x], lcnt[threadIdx.x]);
}

// Fused: centers (per-block, from global sums) + distances + mean (last block writes out)
__global__ __launch_bounds__(256) void k_dist(const float* __restrict__ temb,
                                              const float* __restrict__ tsl,
                                              float* __restrict__ ws,
                                              float* __restrict__ out,
                                              int nrows, float invN) {
    __shared__ float lc[NSEC * D];
    for (int i = threadIdx.x; i < NSEC * D; i += 256) {
        const int s = i >> 8;  // i / D
        lc[i] = ws[WS_SUMS + i] / ws[WS_CNT + s];
    }
    __syncthreads();

    const int lane = threadIdx.x & 63;
    const int wid  = threadIdx.x >> 6;
    const int gw   = blockIdx.x * 4 + wid;
    const int nw   = gridDim.x * 4;

    const float* tp = temb + (size_t)lane * 4;

    auto rowdist = [&](float si, float4 v) -> float {
        int s = (int)floorf(si / SLICE);   // exact reference semantics: divide, floor, clip
        s = s < 0 ? 0 : (s > NSEC - 1 ? NSEC - 1 : s);
        const float4 c = *reinterpret_cast<const float4*>(&lc[s * D + lane * 4]);
        const float dx = v.x - c.x + EPS;
        const float dy = v.y - c.y + EPS;
        const float dz = v.z - c.z + EPS;
        const float dw = v.w - c.w + EPS;
        float loc = dx * dx + dy * dy + dz * dz + dw * dw;
#pragma unroll
        for (int off = 32; off >= 1; off >>= 1) loc += __shfl_xor(loc, off, 64);
        return loc;   // full row sum-of-squares, replicated across lanes
    };

    float wacc = 0.f;
    int r = gw;
    for (; r + 3 * nw < nrows; r += 4 * nw) {
        const float t0 = tsl[r];
        const float t1 = tsl[r + nw];
        const float t2 = tsl[r + 2 * nw];
        const float t3 = tsl[r + 3 * nw];
        const float4 v0 = *reinterpret_cast<const float4*>(tp + (size_t)r * D);
        const float4 v1 = *reinterpret_cast<const float4*>(tp + (size_t)(r + nw) * D);
        const float4 v2 = *reinterpret_cast<const float4*>(tp + (size_t)(r + 2 * nw) * D);
        const float4 v3 = *reinterpret_cast<const float4*>(tp + (size_t)(r + 3 * nw) * D);
        float l0 = rowdist(t0, v0);
        float l1 = rowdist(t1, v1);
        float l2 = rowdist(t2, v2);
        float l3 = rowdist(t3, v3);
        if (lane == 0) wacc += sqrtf(l0) + sqrtf(l1) + sqrtf(l2) + sqrtf(l3);
    }
    for (; r < nrows; r += nw) {
        float l = rowdist(tsl[r], *reinterpret_cast<const float4*>(tp + (size_t)r * D));
        if (lane == 0) wacc += sqrtf(l);
    }

    __shared__ float wsum[4];
    if (lane == 0) wsum[wid] = wacc;
    __syncthreads();
    if (threadIdx.x == 0) {
        atomicAdd(&ws[WS_DIST], wsum[0] + wsum[1] + wsum[2] + wsum[3]);
        __threadfence();   // make the add visible device-wide before signaling done
        unsigned prev = atomicAdd(reinterpret_cast<unsigned*>(&ws[WS_DONE]), 1u);
        if (prev == gridDim.x - 1) {
            const float tot = atomicAdd(&ws[WS_DIST], 0.0f);  // device-scope coherent read
            out[0] = tot * invN;
        }
    }
}

extern "C" void kernel_launch(void* const* d_in, const int* in_sizes, int n_in,
                              void* d_out, int out_size, void* d_ws, size_t ws_size,
                              hipStream_t stream) {
    const float* semb = (const float*)d_in[0];   // [nS, 256] f32
    const int*   ssec = (const int*)d_in[1];     // [nS] i32
    const float* temb = (const float*)d_in[2];   // [nT, 256] f32
    const float* tsl  = (const float*)d_in[3];   // [nT] f32
    float* ws  = (float*)d_ws;
    float* out = (float*)d_out;
    const int nS = in_sizes[1];
    const int nT = in_sizes[3];

    hipLaunchKernelGGL(k_zero, dim3((WS_ZERO_FLOATS + 255) / 256), dim3(256), 0, stream, ws);
    hipLaunchKernelGGL(k_sums, dim3(1024), dim3(256), 0, stream, semb, ssec, ws, nS);
    hipLaunchKernelGGL(k_dist, dim3(2048), dim3(256), 0, stream, temb, tsl, ws, out,
                       nT, 1.0f / (float)nT);
}

// Round 5
// 112.857 us; speedup vs baseline: 1.7968x; 1.7968x over previous
//
#include <hip/hip_runtime.h>
#include <math.h>

#define D      256
#define NSEC   10
#define EPS    1e-6f
#define SLICE  0.1f

// ws float layout
#define WS_SUMS 0                      // [0,2560) per-sector sums
#define WS_CNT  (NSEC * D)             // [2560,2570) per-sector counts
#define WS_DIST (NSEC * D + NSEC)      // [2570] distance accumulator
#define WS_ZERO_FLOATS (NSEC * D + NSEC + 1)

__global__ void k_zero(float* __restrict__ ws) {
    int i = blockIdx.x * blockDim.x + threadIdx.x;
    if (i < WS_ZERO_FLOATS) ws[i] = 0.f;
}

__global__ __launch_bounds__(256) void k_sums(const float* __restrict__ emb,
                                              const int* __restrict__ sec,
                                              float* __restrict__ ws, int nrows) {
    const int lane = threadIdx.x & 63;
    const int wid  = threadIdx.x >> 6;          // 0..3
    const int gw   = blockIdx.x * 4 + wid;      // global wave id
    const int nw   = gridDim.x * 4;

    float4 acc[NSEC];
    float  cnt[NSEC];
#pragma unroll
    for (int s = 0; s < NSEC; ++s) { acc[s] = make_float4(0.f, 0.f, 0.f, 0.f); cnt[s] = 0.f; }

    const float* ep = emb + (size_t)lane * 4;

    auto accum = [&](int sv, float4 v) {
        const int s = __builtin_amdgcn_readfirstlane(sv);  // wave-uniform -> SGPR branch
#pragma unroll
        for (int ss = 0; ss < NSEC; ++ss) {
            if (s == ss) {   // scalar branch; acc index compile-time constant (no scratch)
                acc[ss].x += v.x; acc[ss].y += v.y; acc[ss].z += v.z; acc[ss].w += v.w;
                cnt[ss] += 1.f;
            }
        }
    };

    int r = gw;
    // unroll-4: 4 KB in flight per wave; 16 waves/CU (grid 1024) hides latency
    for (; r + 3 * nw < nrows; r += 4 * nw) {
        const int s0 = sec[r];
        const int s1 = sec[r + nw];
        const int s2 = sec[r + 2 * nw];
        const int s3 = sec[r + 3 * nw];
        const float4 v0 = *reinterpret_cast<const float4*>(ep + (size_t)r * D);
        const float4 v1 = *reinterpret_cast<const float4*>(ep + (size_t)(r + nw) * D);
        const float4 v2 = *reinterpret_cast<const float4*>(ep + (size_t)(r + 2 * nw) * D);
        const float4 v3 = *reinterpret_cast<const float4*>(ep + (size_t)(r + 3 * nw) * D);
        accum(s0, v0); accum(s1, v1); accum(s2, v2); accum(s3, v3);
    }
    for (; r < nrows; r += nw)
        accum(sec[r], *reinterpret_cast<const float4*>(ep + (size_t)r * D));

    __shared__ float lsum[NSEC * D];   // 10 KB -> LDS never caps occupancy
    __shared__ float lcnt[NSEC];
    for (int i = threadIdx.x; i < NSEC * D; i += 256) lsum[i] = 0.f;
    if (threadIdx.x < NSEC) lcnt[threadIdx.x] = 0.f;
    __syncthreads();

    // 4 serialized wave phases: no LDS atomics, no intra-wave address overlap
    for (int w = 0; w < 4; ++w) {
        if (wid == w) {
#pragma unroll
            for (int ss = 0; ss < NSEC; ++ss) {
                float* p = &lsum[ss * D + lane * 4];
                p[0] += acc[ss].x; p[1] += acc[ss].y; p[2] += acc[ss].z; p[3] += acc[ss].w;
                if (lane == 0) lcnt[ss] += cnt[ss];
            }
        }
        __syncthreads();
    }

#pragma unroll
    for (int ss = 0; ss < NSEC; ++ss)
        atomicAdd(&ws[WS_SUMS + ss * D + threadIdx.x], lsum[ss * D + threadIdx.x]);
    if (threadIdx.x < NSEC)
        atomicAdd(&ws[WS_CNT + threadIdx.x], lcnt[threadIdx.x]);
}

// centers recomputed per-block from global sums (10 KB L2 read), then distances.
// NO fence / done-counter: one plain device-scope atomicAdd per block; the
// kernel-launch boundary orders it before k_final.
__global__ __launch_bounds__(256) void k_dist(const float* __restrict__ temb,
                                              const float* __restrict__ tsl,
                                              float* __restrict__ ws, int nrows) {
    __shared__ float lc[NSEC * D];
    for (int i = threadIdx.x; i < NSEC * D; i += 256) {
        const int s = i >> 8;  // i / D
        lc[i] = ws[WS_SUMS + i] / ws[WS_CNT + s];
    }
    __syncthreads();

    const int lane = threadIdx.x & 63;
    const int wid  = threadIdx.x >> 6;
    const int gw   = blockIdx.x * 4 + wid;
    const int nw   = gridDim.x * 4;

    const float* tp = temb + (size_t)lane * 4;

    auto rowdist = [&](float si, float4 v) -> float {
        int s = (int)floorf(si / SLICE);   // exact reference semantics: divide, floor, clip
        s = s < 0 ? 0 : (s > NSEC - 1 ? NSEC - 1 : s);
        const float4 c = *reinterpret_cast<const float4*>(&lc[s * D + lane * 4]);
        const float dx = v.x - c.x + EPS;
        const float dy = v.y - c.y + EPS;
        const float dz = v.z - c.z + EPS;
        const float dw = v.w - c.w + EPS;
        float loc = dx * dx + dy * dy + dz * dz + dw * dw;
#pragma unroll
        for (int off = 32; off >= 1; off >>= 1) loc += __shfl_xor(loc, off, 64);
        return loc;   // full row sum-of-squares, replicated across lanes
    };

    float wacc = 0.f;
    int r = gw;
    for (; r + 3 * nw < nrows; r += 4 * nw) {
        const float t0 = tsl[r];
        const float t1 = tsl[r + nw];
        const float t2 = tsl[r + 2 * nw];
        const float t3 = tsl[r + 3 * nw];
        const float4 v0 = *reinterpret_cast<const float4*>(tp + (size_t)r * D);
        const float4 v1 = *reinterpret_cast<const float4*>(tp + (size_t)(r + nw) * D);
        const float4 v2 = *reinterpret_cast<const float4*>(tp + (size_t)(r + 2 * nw) * D);
        const float4 v3 = *reinterpret_cast<const float4*>(tp + (size_t)(r + 3 * nw) * D);
        float l0 = rowdist(t0, v0);
        float l1 = rowdist(t1, v1);
        float l2 = rowdist(t2, v2);
        float l3 = rowdist(t3, v3);
        if (lane == 0) wacc += sqrtf(l0) + sqrtf(l1) + sqrtf(l2) + sqrtf(l3);
    }
    for (; r < nrows; r += nw) {
        float l = rowdist(tsl[r], *reinterpret_cast<const float4*>(tp + (size_t)r * D));
        if (lane == 0) wacc += sqrtf(l);
    }

    __shared__ float wsum[4];
    if (lane == 0) wsum[wid] = wacc;
    __syncthreads();
    if (threadIdx.x == 0)
        atomicAdd(&ws[WS_DIST], wsum[0] + wsum[1] + wsum[2] + wsum[3]);
}

__global__ void k_final(const float* __restrict__ ws, float* __restrict__ out, float invN) {
    out[0] = ws[WS_DIST] * invN;
}

extern "C" void kernel_launch(void* const* d_in, const int* in_sizes, int n_in,
                              void* d_out, int out_size, void* d_ws, size_t ws_size,
                              hipStream_t stream) {
    const float* semb = (const float*)d_in[0];   // [nS, 256] f32
    const int*   ssec = (const int*)d_in[1];     // [nS] i32
    const float* temb = (const float*)d_in[2];   // [nT, 256] f32
    const float* tsl  = (const float*)d_in[3];   // [nT] f32
    float* ws  = (float*)d_ws;
    float* out = (float*)d_out;
    const int nS = in_sizes[1];
    const int nT = in_sizes[3];

    hipLaunchKernelGGL(k_zero, dim3((WS_ZERO_FLOATS + 255) / 256), dim3(256), 0, stream, ws);
    hipLaunchKernelGGL(k_sums, dim3(1024), dim3(256), 0, stream, semb, ssec, ws, nS);
    hipLaunchKernelGGL(k_dist, dim3(1024), dim3(256), 0, stream, temb, tsl, ws, nT);
    hipLaunchKernelGGL(k_final, dim3(1), dim3(1), 0, stream, ws, out, 1.0f / (float)nT);
}

// Round 6
// 101.489 us; speedup vs baseline: 1.9981x; 1.1120x over previous
//
#include <hip/hip_runtime.h>
#include <math.h>

#define D      256
#define NSEC   10
#define EPS    1e-6f
#define SLICE  0.1f

// ws float layout
#define WS_SUMS 0                      // [0,2560) per-sector sums
#define WS_CNT  (NSEC * D)             // [2560,2570) per-sector counts
#define WS_PART (NSEC * D + NSEC)      // [2570,2826) per-block distance partials (256)
#define WS_ZERO_FLOATS (NSEC * D + NSEC)   // only sums+counts need zeroing

#define DIST_BLOCKS 256

__global__ void k_zero(float* __restrict__ ws) {
    int i = blockIdx.x * blockDim.x + threadIdx.x;
    if (i < WS_ZERO_FLOATS) ws[i] = 0.f;
}

__global__ __launch_bounds__(256) void k_sums(const float* __restrict__ emb,
                                              const int* __restrict__ sec,
                                              float* __restrict__ ws, int nrows) {
    const int lane = threadIdx.x & 63;
    const int wid  = threadIdx.x >> 6;          // 0..3
    const int gw   = blockIdx.x * 4 + wid;      // global wave id
    const int nw   = gridDim.x * 4;

    float4 acc[NSEC];
    float  cnt[NSEC];
#pragma unroll
    for (int s = 0; s < NSEC; ++s) { acc[s] = make_float4(0.f, 0.f, 0.f, 0.f); cnt[s] = 0.f; }

    const float* ep = emb + (size_t)lane * 4;

    auto accum = [&](int sv, float4 v) {
        const int s = __builtin_amdgcn_readfirstlane(sv);  // wave-uniform -> SGPR branch
#pragma unroll
        for (int ss = 0; ss < NSEC; ++ss) {
            if (s == ss) {   // scalar branch; acc index compile-time constant (no scratch)
                acc[ss].x += v.x; acc[ss].y += v.y; acc[ss].z += v.z; acc[ss].w += v.w;
                cnt[ss] += 1.f;
            }
        }
    };

    int r = gw;
    for (; r + 3 * nw < nrows; r += 4 * nw) {
        const int s0 = sec[r];
        const int s1 = sec[r + nw];
        const int s2 = sec[r + 2 * nw];
        const int s3 = sec[r + 3 * nw];
        const float4 v0 = *reinterpret_cast<const float4*>(ep + (size_t)r * D);
        const float4 v1 = *reinterpret_cast<const float4*>(ep + (size_t)(r + nw) * D);
        const float4 v2 = *reinterpret_cast<const float4*>(ep + (size_t)(r + 2 * nw) * D);
        const float4 v3 = *reinterpret_cast<const float4*>(ep + (size_t)(r + 3 * nw) * D);
        accum(s0, v0); accum(s1, v1); accum(s2, v2); accum(s3, v3);
    }
    for (; r < nrows; r += nw)
        accum(sec[r], *reinterpret_cast<const float4*>(ep + (size_t)r * D));

    __shared__ float lsum[NSEC * D];   // 10 KB
    __shared__ float lcnt[NSEC];
    for (int i = threadIdx.x; i < NSEC * D; i += 256) lsum[i] = 0.f;
    if (threadIdx.x < NSEC) lcnt[threadIdx.x] = 0.f;
    __syncthreads();

    for (int w = 0; w < 4; ++w) {
        if (wid == w) {
#pragma unroll
            for (int ss = 0; ss < NSEC; ++ss) {
                float* p = &lsum[ss * D + lane * 4];
                p[0] += acc[ss].x; p[1] += acc[ss].y; p[2] += acc[ss].z; p[3] += acc[ss].w;
                if (lane == 0) lcnt[ss] += cnt[ss];
            }
        }
        __syncthreads();
    }

    // distributed atomics (2560 distinct addresses) — parallel across L3 banks, OK
#pragma unroll
    for (int ss = 0; ss < NSEC; ++ss)
        atomicAdd(&ws[WS_SUMS + ss * D + threadIdx.x], lsum[ss * D + threadIdx.x]);
    if (threadIdx.x < NSEC)
        atomicAdd(&ws[WS_CNT + threadIdx.x], lcnt[threadIdx.x]);
}

// 256 blocks x 1024 threads (2 blocks/CU, 32 waves/CU). Prologue runs 256x,
// epilogue is a PLAIN STORE to a private slot — no same-address atomics at all.
__global__ __launch_bounds__(1024) void k_dist(const float* __restrict__ temb,
                                               const float* __restrict__ tsl,
                                               float* __restrict__ ws, int nrows) {
    __shared__ float lc[NSEC * D];
    for (int i = threadIdx.x; i < NSEC * D; i += 1024) {
        const int s = i >> 8;  // i / D
        lc[i] = ws[WS_SUMS + i] / ws[WS_CNT + s];
    }
    __syncthreads();

    const int lane = threadIdx.x & 63;
    const int wid  = threadIdx.x >> 6;            // 0..15
    const int gw   = blockIdx.x * 16 + wid;       // global wave id (4096 total)
    const int nw   = gridDim.x * 16;

    const float* tp = temb + (size_t)lane * 4;

    auto rowdist = [&](float si, float4 v) -> float {
        int s = (int)floorf(si / SLICE);   // exact reference semantics: divide, floor, clip
        s = s < 0 ? 0 : (s > NSEC - 1 ? NSEC - 1 : s);
        const float4 c = *reinterpret_cast<const float4*>(&lc[s * D + lane * 4]);
        const float dx = v.x - c.x + EPS;
        const float dy = v.y - c.y + EPS;
        const float dz = v.z - c.z + EPS;
        const float dw = v.w - c.w + EPS;
        float loc = dx * dx + dy * dy + dz * dz + dw * dw;
#pragma unroll
        for (int off = 32; off >= 1; off >>= 1) loc += __shfl_xor(loc, off, 64);
        return loc;
    };

    float wacc = 0.f;
    int r = gw;
    for (; r + 3 * nw < nrows; r += 4 * nw) {
        const float t0 = tsl[r];
        const float t1 = tsl[r + nw];
        const float t2 = tsl[r + 2 * nw];
        const float t3 = tsl[r + 3 * nw];
        const float4 v0 = *reinterpret_cast<const float4*>(tp + (size_t)r * D);
        const float4 v1 = *reinterpret_cast<const float4*>(tp + (size_t)(r + nw) * D);
        const float4 v2 = *reinterpret_cast<const float4*>(tp + (size_t)(r + 2 * nw) * D);
        const float4 v3 = *reinterpret_cast<const float4*>(tp + (size_t)(r + 3 * nw) * D);
        float l0 = rowdist(t0, v0);
        float l1 = rowdist(t1, v1);
        float l2 = rowdist(t2, v2);
        float l3 = rowdist(t3, v3);
        if (lane == 0) wacc += sqrtf(l0) + sqrtf(l1) + sqrtf(l2) + sqrtf(l3);
    }
    for (; r < nrows; r += nw) {
        float l = rowdist(tsl[r], *reinterpret_cast<const float4*>(tp + (size_t)r * D));
        if (lane == 0) wacc += sqrtf(l);
    }

    __shared__ float wsum[16];
    if (lane == 0) wsum[wid] = wacc;
    __syncthreads();
    if (threadIdx.x == 0) {
        float t = 0.f;
#pragma unroll
        for (int k = 0; k < 16; ++k) t += wsum[k];
        ws[WS_PART + blockIdx.x] = t;   // plain store, private slot
    }
}

// single block reduces the 256 partials
__global__ __launch_bounds__(256) void k_final(const float* __restrict__ ws,
                                               float* __restrict__ out, float invN) {
    float v = ws[WS_PART + threadIdx.x];
#pragma unroll
    for (int off = 32; off >= 1; off >>= 1) v += __shfl_xor(v, off, 64);
    __shared__ float s4[4];
    if ((threadIdx.x & 63) == 0) s4[threadIdx.x >> 6] = v;
    __syncthreads();
    if (threadIdx.x == 0) out[0] = (s4[0] + s4[1] + s4[2] + s4[3]) * invN;
}

extern "C" void kernel_launch(void* const* d_in, const int* in_sizes, int n_in,
                              void* d_out, int out_size, void* d_ws, size_t ws_size,
                              hipStream_t stream) {
    const float* semb = (const float*)d_in[0];   // [nS, 256] f32
    const int*   ssec = (const int*)d_in[1];     // [nS] i32
    const float* temb = (const float*)d_in[2];   // [nT, 256] f32
    const float* tsl  = (const float*)d_in[3];   // [nT] f32
    float* ws  = (float*)d_ws;
    float* out = (float*)d_out;
    const int nS = in_sizes[1];
    const int nT = in_sizes[3];

    hipLaunchKernelGGL(k_zero, dim3((WS_ZERO_FLOATS + 255) / 256), dim3(256), 0, stream, ws);
    hipLaunchKernelGGL(k_sums, dim3(1024), dim3(256), 0, stream, semb, ssec, ws, nS);
    hipLaunchKernelGGL(k_dist, dim3(DIST_BLOCKS), dim3(1024), 0, stream, temb, tsl, ws, nT);
    hipLaunchKernelGGL(k_final, dim3(1), dim3(256), 0, stream, ws, out, 1.0f / (float)nT);
}

// Round 7
// 100.796 us; speedup vs baseline: 2.0119x; 1.0069x over previous
//
#include <hip/hip_runtime.h>
#include <math.h>

#define D      256
#define NSEC   10
#define EPS    1e-6f
#define SLICE  0.1f

// ws float layout
#define WS_SUMS 0                      // [0,2560) per-sector sums
#define WS_CNT  (NSEC * D)             // [2560,2570) per-sector counts
#define WS_PART (NSEC * D + NSEC)      // [2570,2826) per-block distance partials (256)
#define WS_ZERO_FLOATS (NSEC * D + NSEC)   // only sums+counts need zeroing

#define DIST_BLOCKS 256

__global__ void k_zero(float* __restrict__ ws) {
    int i = blockIdx.x * blockDim.x + threadIdx.x;
    if (i < WS_ZERO_FLOATS) ws[i] = 0.f;
}

__global__ __launch_bounds__(256) void k_sums(const float* __restrict__ emb,
                                              const int* __restrict__ sec,
                                              float* __restrict__ ws, int nrows) {
    const int lane = threadIdx.x & 63;
    const int wid  = threadIdx.x >> 6;          // 0..3
    const int gw   = blockIdx.x * 4 + wid;      // global wave id
    const int nw   = gridDim.x * 4;

    float4 acc[NSEC];
    float  cnt[NSEC];
#pragma unroll
    for (int s = 0; s < NSEC; ++s) { acc[s] = make_float4(0.f, 0.f, 0.f, 0.f); cnt[s] = 0.f; }

    const float* ep = emb + (size_t)lane * 4;

    auto accum = [&](int sv, float4 v) {
        const int s = __builtin_amdgcn_readfirstlane(sv);  // wave-uniform -> SGPR branch
#pragma unroll
        for (int ss = 0; ss < NSEC; ++ss) {
            if (s == ss) {   // scalar branch; acc index compile-time constant (no scratch)
                acc[ss].x += v.x; acc[ss].y += v.y; acc[ss].z += v.z; acc[ss].w += v.w;
                cnt[ss] += 1.f;
            }
        }
    };

    int r = gw;
    for (; r + 3 * nw < nrows; r += 4 * nw) {
        const int s0 = sec[r];
        const int s1 = sec[r + nw];
        const int s2 = sec[r + 2 * nw];
        const int s3 = sec[r + 3 * nw];
        const float4 v0 = *reinterpret_cast<const float4*>(ep + (size_t)r * D);
        const float4 v1 = *reinterpret_cast<const float4*>(ep + (size_t)(r + nw) * D);
        const float4 v2 = *reinterpret_cast<const float4*>(ep + (size_t)(r + 2 * nw) * D);
        const float4 v3 = *reinterpret_cast<const float4*>(ep + (size_t)(r + 3 * nw) * D);
        accum(s0, v0); accum(s1, v1); accum(s2, v2); accum(s3, v3);
    }
    for (; r < nrows; r += nw)
        accum(sec[r], *reinterpret_cast<const float4*>(ep + (size_t)r * D));

    __shared__ float lsum[NSEC * D];   // 10 KB
    __shared__ float lcnt[NSEC];
    for (int i = threadIdx.x; i < NSEC * D; i += 256) lsum[i] = 0.f;
    if (threadIdx.x < NSEC) lcnt[threadIdx.x] = 0.f;
    __syncthreads();

    for (int w = 0; w < 4; ++w) {
        if (wid == w) {
#pragma unroll
            for (int ss = 0; ss < NSEC; ++ss) {
                float* p = &lsum[ss * D + lane * 4];
                p[0] += acc[ss].x; p[1] += acc[ss].y; p[2] += acc[ss].z; p[3] += acc[ss].w;
                if (lane == 0) lcnt[ss] += cnt[ss];
            }
        }
        __syncthreads();
    }

#pragma unroll
    for (int ss = 0; ss < NSEC; ++ss)
        atomicAdd(&ws[WS_SUMS + ss * D + threadIdx.x], lsum[ss * D + threadIdx.x]);
    if (threadIdx.x < NSEC)
        atomicAdd(&ws[WS_CNT + threadIdx.x], lcnt[threadIdx.x]);
}

// 256 blocks x 1024 threads. __launch_bounds__(1024,4) lifts the VGPR cap to 128
// so 8 rows of loads stay in flight (R4/R5 showed VGPR_Count=28 => serialized
// loads => full latency exposed per row; VALUBusy 7%, HBM 4%).
__global__ __launch_bounds__(1024, 4) void k_dist(const float* __restrict__ temb,
                                                  const float* __restrict__ tsl,
                                                  float* __restrict__ ws, int nrows) {
    __shared__ float lc[NSEC * D];
    for (int i = threadIdx.x; i < NSEC * D; i += 1024) {
        const int s = i >> 8;  // i / D
        lc[i] = ws[WS_SUMS + i] / ws[WS_CNT + s];
    }
    __syncthreads();

    const int lane = threadIdx.x & 63;
    const int wid  = threadIdx.x >> 6;            // 0..15
    const int gw   = blockIdx.x * 16 + wid;       // global wave id (4096 total)
    const int nw   = gridDim.x * 16;

    const float* tp = temb + (size_t)lane * 4;

    float wacc = 0.f;
    int r = gw;
    for (; r + 7 * nw < nrows; r += 8 * nw) {
        // issue ALL independent global loads first (8 sectors + 8 KB embeddings in flight)
        float  t[8];
        float4 v[8];
#pragma unroll
        for (int k = 0; k < 8; ++k) t[k] = tsl[r + k * nw];
#pragma unroll
        for (int k = 0; k < 8; ++k)
            v[k] = *reinterpret_cast<const float4*>(tp + (size_t)(r + k * nw) * D);

        // per-row: center gather + per-lane sum of squares (8 independent)
        float l[8];
#pragma unroll
        for (int k = 0; k < 8; ++k) {
            int s = (int)floorf(t[k] / SLICE);   // exact reference semantics
            s = s < 0 ? 0 : (s > NSEC - 1 ? NSEC - 1 : s);
            const float4 c = *reinterpret_cast<const float4*>(&lc[s * D + lane * 4]);
            const float dx = v[k].x - c.x + EPS;
            const float dy = v[k].y - c.y + EPS;
            const float dz = v[k].z - c.z + EPS;
            const float dw = v[k].w - c.w + EPS;
            l[k] = dx * dx + dy * dy + dz * dz + dw * dw;
        }

        // stage-major shuffle reduce: 8 independent chains per DS-latency window
#pragma unroll
        for (int off = 32; off >= 1; off >>= 1) {
#pragma unroll
            for (int k = 0; k < 8; ++k) l[k] += __shfl_xor(l[k], off, 64);
        }
#pragma unroll
        for (int k = 0; k < 8; ++k) wacc += sqrtf(l[k]);   // all lanes, no divergence
    }
    for (; r < nrows; r += nw) {
        const float si = tsl[r];
        int s = (int)floorf(si / SLICE);
        s = s < 0 ? 0 : (s > NSEC - 1 ? NSEC - 1 : s);
        const float4 vv = *reinterpret_cast<const float4*>(tp + (size_t)r * D);
        const float4 c = *reinterpret_cast<const float4*>(&lc[s * D + lane * 4]);
        const float dx = vv.x - c.x + EPS;
        const float dy = vv.y - c.y + EPS;
        const float dz = vv.z - c.z + EPS;
        const float dw = vv.w - c.w + EPS;
        float loc = dx * dx + dy * dy + dz * dz + dw * dw;
#pragma unroll
        for (int off = 32; off >= 1; off >>= 1) loc += __shfl_xor(loc, off, 64);
        wacc += sqrtf(loc);
    }

    __shared__ float wsum[16];
    if (lane == 0) wsum[wid] = wacc;
    __syncthreads();
    if (threadIdx.x == 0) {
        float t = 0.f;
#pragma unroll
        for (int k = 0; k < 16; ++k) t += wsum[k];
        ws[WS_PART + blockIdx.x] = t;   // plain store, private slot
    }
}

// single block reduces the 256 partials
__global__ __launch_bounds__(256) void k_final(const float* __restrict__ ws,
                                               float* __restrict__ out, float invN) {
    float v = ws[WS_PART + threadIdx.x];
#pragma unroll
    for (int off = 32; off >= 1; off >>= 1) v += __shfl_xor(v, off, 64);
    __shared__ float s4[4];
    if ((threadIdx.x & 63) == 0) s4[threadIdx.x >> 6] = v;
    __syncthreads();
    if (threadIdx.x == 0) out[0] = (s4[0] + s4[1] + s4[2] + s4[3]) * invN;
}

extern "C" void kernel_launch(void* const* d_in, const int* in_sizes, int n_in,
                              void* d_out, int out_size, void* d_ws, size_t ws_size,
                              hipStream_t stream) {
    const float* semb = (const float*)d_in[0];   // [nS, 256] f32
    const int*   ssec = (const int*)d_in[1];     // [nS] i32
    const float* temb = (const float*)d_in[2];   // [nT, 256] f32
    const float* tsl  = (const float*)d_in[3];   // [nT] f32
    float* ws  = (float*)d_ws;
    float* out = (float*)d_out;
    const int nS = in_sizes[1];
    const int nT = in_sizes[3];

    hipLaunchKernelGGL(k_zero, dim3((WS_ZERO_FLOATS + 255) / 256), dim3(256), 0, stream, ws);
    hipLaunchKernelGGL(k_sums, dim3(1024), dim3(256), 0, stream, semb, ssec, ws, nS);
    hipLaunchKernelGGL(k_dist, dim3(DIST_BLOCKS), dim3(1024), 0, stream, temb, tsl, ws, nT);
    hipLaunchKernelGGL(k_final, dim3(1), dim3(256), 0, stream, ws, out, 1.0f / (float)nT);
}